// Round 7
// baseline (57.994 us; speedup 1.0000x reference)
//
#include <hip/hip_runtime.h>
#include <hip/hip_cooperative_groups.h>

namespace cg = cooperative_groups;

#define HH 352
#define WW 1216
#define NBOX 16
#define KCAND 61
#define HN 88    // H/4
#define WN 304   // W/4

#define SLICES 8
#define KGROUPS 2
#define KLEN 32          // ceil(61/2), padded
#define THREADS 256
#define NWAVE (THREADS / 64)

// Single cooperative kernel, 256 blocks = 1/CU (trivially co-resident).
// Phase 1: block (slice, box, kgroup) accumulates KLEN candidate losses over
// a strided pixel subset, block-reduces, stores partial[box][k][slice].
// grid.sync(). Phase 2: the (0, box, 0) block finalizes its own box.
// Deterministic: fixed summation order, no atomics.
__global__ __launch_bounds__(THREADS) void fused_coop_kernel(
    const float* __restrict__ nocs,    // (3, HN, WN)
    const float* __restrict__ dd,      // (HH, WW, 3)
    const int*   __restrict__ boxes,   // (N, 4)
    const float* __restrict__ pc,      // (N, 2)
    const float* __restrict__ bdepth,  // (N,)
    const float* __restrict__ dims,    // (N, 3)
    const float* __restrict__ intr,    // (3, 3)
    float* __restrict__ partial,       // (N, K, S)
    float* __restrict__ out,           // (N, 3)
    int S)
{
    const int slice = blockIdx.x;
    const int box   = blockIdx.y;
    const int kg    = blockIdx.z;
    const int tid   = threadIdx.x;
    const int kbase = kg * KLEN;

    const int x1 = boxes[box*4+0], y1 = boxes[box*4+1];
    const int x2 = boxes[box*4+2], y2 = boxes[box*4+3];
    const int bw = x2 - x1;
    const int npix = bw * (y2 - y1);

    const float fx = intr[0], cx = intr[2], fy = intr[4], cy = intr[5];
    const float ax = (pc[box*2+0] - cx) / fx;
    const float ay = (pc[box*2+1] - cy) / fy;
    const float bd = bdepth[box];
    const float d0 = bd + (0.1f * (float)kbase - 3.0f);
    const float dax = 0.1f * ax;
    const float day = 0.1f * ay;

    // exact magic-multiply division p/bw (p < 2^15, bw <= 200)
    const unsigned magic = (bw > 1) ? (0xFFFFFFFFu / (unsigned)bw + 1u) : 0u;

    float acc[KLEN];
#pragma unroll
    for (int k = 0; k < KLEN; ++k) acc[k] = 0.f;

    const int stride = S * THREADS;
    for (int p = slice * THREADS + tid; p < npix; p += stride) {
        unsigned q = (bw > 1) ? __umulhi((unsigned)p, magic) : (unsigned)p;
        const int r   = p - (int)q * bw;
        const int row = y1 + (int)q;
        const int x   = x1 + r;

        // ---- issue ALL loads up front (independent of dz) for MLP ----
        const float* dp = dd + ((size_t)row * WW + x) * 3;
        const float dz = dp[2];
        const float dp0 = dp[0], dp1 = dp[1];

        const int ry  = row & 3;
        const int yy0 = (row >> 2) + ((ry >= 2) ? 0 : -1);
        const float wy = 0.125f + 0.25f * (float)((ry + 2) & 3);
        const int ya = max(yy0, 0);
        const int yb = min(yy0 + 1, HN - 1);

        const int rx  = x & 3;
        const int xx0 = (x >> 2) + ((rx >= 2) ? 0 : -1);
        const float wx = 0.125f + 0.25f * (float)((rx + 2) & 3);
        const int xa = max(xx0, 0);
        const int xb = min(xx0 + 1, WN - 1);

        float b0, b1, b2;
        {
            const float* n0 = nocs;
            const float* n1 = nocs + (HN * WN);
            const float* n2 = nocs + 2 * (HN * WN);
            const int ia = ya*WN + xa, ib = ya*WN + xb;
            const int ic = yb*WN + xa, id_ = yb*WN + xb;
            const float a00 = n0[ia], a01 = n0[ib], a10 = n0[ic], a11 = n0[id_];
            const float b00 = n1[ia], b01 = n1[ib], b10 = n1[ic], b11 = n1[id_];
            const float c00 = n2[ia], c01 = n2[ib], c10 = n2[ic], c11 = n2[id_];
            const float av0 = a00 + (a01 - a00) * wx, av1 = a10 + (a11 - a10) * wx;
            const float bv0 = b00 + (b01 - b00) * wx, bv1 = b10 + (b11 - b10) * wx;
            const float cv0 = c00 + (c01 - c00) * wx, cv1 = c10 + (c11 - c10) * wx;
            b0 = (av0 + (av1 - av0) * wy) - dp0;
            b1 = (bv0 + (bv1 - bv0) * wy) - dp1;
            b2 = (cv0 + (cv1 - cv0) * wy) - dz;
        }

        if (dz >= 1.0f) {   // empty mask (true for ~98% of pixels)
            float t0 = fmaf(ax, d0, b0);
            float t1 = fmaf(ay, d0, b1);
            float t2 = b2 + d0;
#pragma unroll
            for (int k = 0; k < KLEN; ++k) {
                acc[k] += fabsf(t0) + fabsf(t1) + fabsf(t2);
                t0 += dax;
                t1 += day;
                t2 += 0.1f;
            }
        }
    }

    // block reduce: per-wave shuffle, lane0 -> LDS, then cross-wave sum
    const int lane = tid & 63;
    const int wave = tid >> 6;
    __shared__ float wbuf[NWAVE][KLEN];
#pragma unroll
    for (int k = 0; k < KLEN; ++k) {
        float v = acc[k];
        for (int off = 32; off; off >>= 1) v += __shfl_xor(v, off, 64);
        if (lane == 0) wbuf[wave][k] = v;
    }
    __syncthreads();
    if (tid < KLEN && kbase + tid < KCAND) {
        float s = 0.f;
#pragma unroll
        for (int w = 0; w < NWAVE; ++w) s += wbuf[w][tid];
        partial[((size_t)box * KCAND + (kbase + tid)) * S + slice] = s;
    }

    // ---- grid-wide barrier (device-scope visibility) ----
    cg::this_grid().sync();

    // ---- phase 2: block (0, box, 0) finalizes its own box ----
    if (slice != 0 || kg != 0 || tid >= 64) return;

    float loss = INFINITY;
    int kk = lane;
    if (lane < KCAND) {
        const float* pp = partial + ((size_t)box * KCAND + lane) * S;
        float s = 0.f;
#pragma unroll 8
        for (int sl = 0; sl < S; ++sl) s += pp[sl];
        loss = s;
    }
    // wave argmin, ties -> smaller k (matches jnp.argmin)
    for (int off = 1; off < 64; off <<= 1) {
        const float ol = __shfl_xor(loss, off, 64);
        const int   ok = __shfl_xor(kk,   off, 64);
        if (ol < loss || (ol == loss && ok < kk)) { loss = ol; kk = ok; }
    }
    if (lane == 0) {
        const float dk = bd + (0.1f * (float)kk - 3.0f);
        out[box*3+0] = ax * dk;
        out[box*3+1] = ay * dk + dims[box*3+1] * 0.5f;
        out[box*3+2] = dk;
    }
}

extern "C" void kernel_launch(void* const* d_in, const int* in_sizes, int n_in,
                              void* d_out, int out_size, void* d_ws, size_t ws_size,
                              hipStream_t stream) {
    const float* nocs  = (const float*)d_in[0];
    const float* dd    = (const float*)d_in[1];
    const int*   boxes = (const int*)d_in[2];
    const float* pc    = (const float*)d_in[3];
    const float* bd    = (const float*)d_in[4];
    const float* dims  = (const float*)d_in[5];
    const float* intr  = (const float*)d_in[6];
    float* out     = (float*)d_out;
    float* partial = (float*)d_ws;

    int S = SLICES;
    while (S > 1 && (size_t)NBOX * KCAND * S * sizeof(float) > ws_size) S >>= 1;

    void* args[] = { (void*)&nocs, (void*)&dd, (void*)&boxes, (void*)&pc,
                     (void*)&bd, (void*)&dims, (void*)&intr,
                     (void*)&partial, (void*)&out, (void*)&S };
    hipLaunchCooperativeKernel((void*)fused_coop_kernel,
                               dim3(S, NBOX, KGROUPS), dim3(THREADS),
                               args, 0, stream);
}

// Round 8
// 26.710 us; speedup vs baseline: 2.1712x; 2.1712x over previous
//
#include <hip/hip_runtime.h>

#define HH 352
#define WW 1216
#define NBOX 16
#define KCAND 61
#define HN 88    // H/4
#define WN 304   // W/4

#define SLICES 8
#define KGROUPS 2
#define KLEN 32          // ceil(61/2), padded
#define THREADS 256
#define NWAVE (THREADS / 64)

// Single regular kernel + 64B memset node. Block (slice, box, kg) accumulates
// KLEN candidate losses, block-reduces, stores partial[box][k][slice] with
// agent scope, then bumps counter[box]. The 16th arrival for a box (which
// already holds that box's constants in registers) performs the argmin and
// writes the output. Per-box counters -> 16-way contention max (vs R4's 2048).
__global__ __launch_bounds__(THREADS) void fused_kernel(
    const float* __restrict__ nocs,    // (3, HN, WN)
    const float* __restrict__ dd,      // (HH, WW, 3)
    const int*   __restrict__ boxes,   // (N, 4)
    const float* __restrict__ pc,      // (N, 2)
    const float* __restrict__ bdepth,  // (N,)
    const float* __restrict__ dims,    // (N, 3)
    const float* __restrict__ intr,    // (3, 3)
    float* __restrict__ partial,       // (N, K, S)
    unsigned* __restrict__ counters,   // (N,) zeroed per call by memset node
    float* __restrict__ out,           // (N, 3)
    int S)
{
    const int slice = blockIdx.x;
    const int box   = blockIdx.y;
    const int kg    = blockIdx.z;
    const int tid   = threadIdx.x;
    const int kbase = kg * KLEN;
    const int blocks_per_box = S * KGROUPS;

    const int x1 = boxes[box*4+0], y1 = boxes[box*4+1];
    const int x2 = boxes[box*4+2], y2 = boxes[box*4+3];
    const int bw = x2 - x1;
    const int npix = bw * (y2 - y1);

    const float fx = intr[0], cx = intr[2], fy = intr[4], cy = intr[5];
    const float ax = (pc[box*2+0] - cx) / fx;
    const float ay = (pc[box*2+1] - cy) / fy;
    const float bd = bdepth[box];
    const float d0 = bd + (0.1f * (float)kbase - 3.0f);
    const float dax = 0.1f * ax;
    const float day = 0.1f * ay;

    // exact magic-multiply division p/bw (p < 2^15, bw <= 200)
    const unsigned magic = (bw > 1) ? (0xFFFFFFFFu / (unsigned)bw + 1u) : 0u;

    float acc[KLEN];
#pragma unroll
    for (int k = 0; k < KLEN; ++k) acc[k] = 0.f;

    const int stride = S * THREADS;
    for (int p = slice * THREADS + tid; p < npix; p += stride) {
        unsigned q = (bw > 1) ? __umulhi((unsigned)p, magic) : (unsigned)p;
        const int r   = p - (int)q * bw;
        const int row = y1 + (int)q;
        const int x   = x1 + r;

        // issue all loads up front (independent of dz) for MLP
        const float* dp = dd + ((size_t)row * WW + x) * 3;
        const float dz = dp[2];
        const float dp0 = dp[0], dp1 = dp[1];

        const int ry  = row & 3;
        const int yy0 = (row >> 2) + ((ry >= 2) ? 0 : -1);
        const float wy = 0.125f + 0.25f * (float)((ry + 2) & 3);
        const int ya = max(yy0, 0);
        const int yb = min(yy0 + 1, HN - 1);

        const int rx  = x & 3;
        const int xx0 = (x >> 2) + ((rx >= 2) ? 0 : -1);
        const float wx = 0.125f + 0.25f * (float)((rx + 2) & 3);
        const int xa = max(xx0, 0);
        const int xb = min(xx0 + 1, WN - 1);

        float b0, b1, b2;
        {
            const float* n0 = nocs;
            const float* n1 = nocs + (HN * WN);
            const float* n2 = nocs + 2 * (HN * WN);
            const int ia = ya*WN + xa, ib = ya*WN + xb;
            const int ic = yb*WN + xa, id_ = yb*WN + xb;
            const float a00 = n0[ia], a01 = n0[ib], a10 = n0[ic], a11 = n0[id_];
            const float b00 = n1[ia], b01 = n1[ib], b10 = n1[ic], b11 = n1[id_];
            const float c00 = n2[ia], c01 = n2[ib], c10 = n2[ic], c11 = n2[id_];
            const float av0 = a00 + (a01 - a00) * wx, av1 = a10 + (a11 - a10) * wx;
            const float bv0 = b00 + (b01 - b00) * wx, bv1 = b10 + (b11 - b10) * wx;
            const float cv0 = c00 + (c01 - c00) * wx, cv1 = c10 + (c11 - c10) * wx;
            b0 = (av0 + (av1 - av0) * wy) - dp0;
            b1 = (bv0 + (bv1 - bv0) * wy) - dp1;
            b2 = (cv0 + (cv1 - cv0) * wy) - dz;
        }

        if (dz >= 1.0f) {   // empty mask (true for most pixels)
            float t0 = fmaf(ax, d0, b0);
            float t1 = fmaf(ay, d0, b1);
            float t2 = b2 + d0;
#pragma unroll
            for (int k = 0; k < KLEN; ++k) {
                acc[k] += fabsf(t0) + fabsf(t1) + fabsf(t2);
                t0 += dax;
                t1 += day;
                t2 += 0.1f;
            }
        }
    }

    // block reduce: per-wave shuffle, lane0 -> LDS, then cross-wave sum
    const int lane = tid & 63;
    const int wave = tid >> 6;
    __shared__ float wbuf[NWAVE][KLEN];
    __shared__ int lastflag;
#pragma unroll
    for (int k = 0; k < KLEN; ++k) {
        float v = acc[k];
        for (int off = 32; off; off >>= 1) v += __shfl_xor(v, off, 64);
        if (lane == 0) wbuf[wave][k] = v;
    }
    __syncthreads();
    if (tid < KLEN && kbase + tid < KCAND) {
        float s = 0.f;
#pragma unroll
        for (int w = 0; w < NWAVE; ++w) s += wbuf[w][tid];
        __hip_atomic_store(&partial[((size_t)box * KCAND + (kbase + tid)) * S + slice],
                           s, __ATOMIC_RELAXED, __HIP_MEMORY_SCOPE_AGENT);
    }
    // tid 0..31 (the storers) and tid 0 (the RMW) are the same wave: the
    // release RMW orders the wave's prior sc1 stores before the count bump.
    if (tid == 0) {
        unsigned prev = __hip_atomic_fetch_add(&counters[box], 1u, __ATOMIC_ACQ_REL,
                                               __HIP_MEMORY_SCOPE_AGENT);
        lastflag = (prev == (unsigned)(blocks_per_box - 1)) ? 1 : 0;
    }
    __syncthreads();
    if (!lastflag || tid >= 64) return;

    // ---- last arrival for this box: finalize (constants already live) ----
    float loss = INFINITY;
    int kk = lane;
    if (lane < KCAND) {
        const float* pp = partial + ((size_t)box * KCAND + lane) * S;
        float s = 0.f;
#pragma unroll 8
        for (int sl = 0; sl < S; ++sl)
            s += __hip_atomic_load(&pp[sl], __ATOMIC_RELAXED,
                                   __HIP_MEMORY_SCOPE_AGENT);
        loss = s;
    }
    // wave argmin, ties -> smaller k (matches jnp.argmin)
    for (int off = 1; off < 64; off <<= 1) {
        const float ol = __shfl_xor(loss, off, 64);
        const int   ok = __shfl_xor(kk,   off, 64);
        if (ol < loss || (ol == loss && ok < kk)) { loss = ol; kk = ok; }
    }
    if (lane == 0) {
        const float dk = bd + (0.1f * (float)kk - 3.0f);
        out[box*3+0] = ax * dk;
        out[box*3+1] = ay * dk + dims[box*3+1] * 0.5f;
        out[box*3+2] = dk;
    }
}

extern "C" void kernel_launch(void* const* d_in, const int* in_sizes, int n_in,
                              void* d_out, int out_size, void* d_ws, size_t ws_size,
                              hipStream_t stream) {
    const float* nocs  = (const float*)d_in[0];
    const float* dd    = (const float*)d_in[1];
    const int*   boxes = (const int*)d_in[2];
    const float* pc    = (const float*)d_in[3];
    const float* bd    = (const float*)d_in[4];
    const float* dims  = (const float*)d_in[5];
    const float* intr  = (const float*)d_in[6];
    float* out = (float*)d_out;

    unsigned* counters = (unsigned*)d_ws;                    // 16*4B @ offset 0
    float* partial     = (float*)((char*)d_ws + 256);        // aligned

    int S = SLICES;
    while (S > 1 && 256 + (size_t)NBOX * KCAND * S * sizeof(float) > ws_size) S >>= 1;

    hipMemsetAsync(counters, 0, NBOX * sizeof(unsigned), stream);  // graph-safe

    fused_kernel<<<dim3(S, NBOX, KGROUPS), THREADS, 0, stream>>>(
        nocs, dd, boxes, pc, bd, dims, intr, partial, counters, out, S);
}